// Round 20
// baseline (150.900 us; speedup 1.0000x reference)
//
#include <hip/hip_runtime.h>

// CrossAttentionAdapter: softmax over a SINGLETON axis => attn == 1 =>
// out[b,p,:] = (((x@Wm^T+bm)@Wv^T+bv)@Wo_mha^T+bo_mha)@Wo^T+bo, independent of p.
// r20 = r18 (best, 132.4) + BLOCK-SPECIALIZED packing: G1-G3 launch 576 blocks;
// blocks 0-511 run the GEMM (identical to r18), blocks 512-575 ONLY pack the
// next GEMM's weights concurrently (the serial CVT tail was ~3.4 us/GEMM of
// pure streaming riding after the epilogue). Pack blocks exit before any
// barrier. GEMM: A via 5-deep LDS ring (swizzled, rule #21); B via packed-
// fragment depth-4 register ring (r15 win); counted vmcnt 18/12/6/0.

#define BM 64
#define BN 64
#define BK 64
#define NA 5
#define GEMM_BLOCKS 512
#define PACK_BLOCKS 64

typedef __attribute__((ext_vector_type(8))) __bf16 bf16x8;
typedef __attribute__((ext_vector_type(8))) unsigned short u16x8;
typedef __attribute__((ext_vector_type(4))) float f32x4;

__device__ __forceinline__ unsigned short f2bf(float f) {
  unsigned int u = __float_as_uint(f);
  u += 0x7FFFu + ((u >> 16) & 1u);   // RNE
  return (unsigned short)(u >> 16);
}

__device__ __forceinline__ u16x8 cvt8(float4 v0, float4 v1) {
  u16x8 o;
  o[0] = f2bf(v0.x); o[1] = f2bf(v0.y); o[2] = f2bf(v0.z); o[3] = f2bf(v0.w);
  o[4] = f2bf(v1.x); o[5] = f2bf(v1.y); o[6] = f2bf(v1.z); o[7] = f2bf(v1.w);
  return o;
}

// Pack one 8-elem unit of row-major W[N][K] (f32) into MFMA-fragment order:
// frag = (n>>4)*(K/32) + (k>>5); lane = ((k>>3)&3)*16 + (n&15); 16B per lane.
template <int KLOG2>
__device__ __forceinline__ void pack_w8(const float* __restrict__ src,
                                        unsigned short* __restrict__ dst,
                                        size_t u) {
  const size_t n = u >> (KLOG2 - 3);
  const size_t ko = u & (((size_t)1 << (KLOG2 - 3)) - 1);   // k/8
  const float4 v0 = reinterpret_cast<const float4*>(src)[u * 2];
  const float4 v1 = reinterpret_cast<const float4*>(src)[u * 2 + 1];
  const size_t frag = (n >> 4) * ((size_t)1 << (KLOG2 - 5)) + (ko >> 2);
  const size_t lane = ((ko & 3) << 4) + (n & 15);
  reinterpret_cast<u16x8*>(dst)[frag * 64 + lane] = cvt8(v0, v1);
}

// X (1024x1024) -> bf16 row-major; Wm (2048x1024) -> packed fragments.
__global__ __launch_bounds__(256) void cvt_xw(const float* __restrict__ x,
                                              const float* __restrict__ wm,
                                              unsigned short* __restrict__ xb,
                                              unsigned short* __restrict__ wmb) {
  size_t u = (size_t)blockIdx.x * 256 + threadIdx.x;   // 262144 threads
  for (; u < 393216; u += 262144) {
    if (u < 131072) {
      const float4 v0 = reinterpret_cast<const float4*>(x)[u * 2];
      const float4 v1 = reinterpret_cast<const float4*>(x)[u * 2 + 1];
      reinterpret_cast<u16x8*>(xb)[u] = cvt8(v0, v1);
    } else {
      pack_w8<10>(wm, wmb, u - 131072);
    }
  }
}

__device__ __forceinline__ void gload_lds16(const void* g, void* l) {
  __builtin_amdgcn_global_load_lds(
      (const __attribute__((address_space(1))) void*)g,
      (__attribute__((address_space(3))) void*)l, 16, 0, 0);
}

// C = A (MxK bf16 row-major) * W^T + bias; Wp = packed fragments; K = NT*64.
// A: 5-deep LDS ring (swizzled source col, rule #21). B: 4-slot VGPR ring,
// statically indexed (full unroll). 6 vmem ops/tile (2 gload_lds + 4 b128);
// counted waits: steady vmcnt(18) (3 tiles in flight), tails 12/6/0.
// EPI=0: bf16 store. EPI=1: fused x32 broadcast via LDS re-stage.
// CVT: blocks [512,576) pack the NEXT GEMM's weights concurrently and exit.
template <int NT, int EPI, bool CVT>
__global__ __launch_bounds__(256, 3) void gemm_bt(
    const unsigned short* __restrict__ A, const unsigned short* __restrict__ Wp,
    const float* __restrict__ bias, void* __restrict__ outp,
    const float* __restrict__ cvt_src, unsigned short* __restrict__ cvt_dst,
    int cvt_nu) {
  __shared__ __attribute__((aligned(16))) unsigned short As[NA][BM * BK];
  const int tid = threadIdx.x;
  const int bid = blockIdx.x;

  if (CVT && bid >= GEMM_BLOCKS) {   // pack-only block: no barriers, exit
    size_t u = (size_t)(bid - GEMM_BLOCKS) * 256 + tid;
    for (; u < (size_t)cvt_nu; u += PACK_BLOCKS * 256)
      pack_w8<11>(cvt_src, cvt_dst, u);
    return;
  }

  const int lane = tid & 63;
  const int wid = tid >> 6;          // 4 waves, 2x2
  const int rm = (wid >> 1) * 32;    // wave row group
  const int cn = (wid & 1) * 32;     // wave col group
  // XCD = bid&7 owns 4 N-tiles (256-col W panel, L2-resident over 16 M-blocks)
  const int bn0 = ((bid & 7) * 4 + (bid >> 7)) * BN;
  const int bm0 = ((bid >> 3) & 15) * BM;
  const int l15 = lane & 15;
  const int l4 = lane >> 4;
  const int lr = lane >> 3;
  const int lc = lane & 7;
  const int scol = ((lc ^ lr) << 3);   // pre-swizzled A source col (rule #21)
  const int KT = NT * 2;               // k-fragments per n-tile row
  const size_t Kz = (size_t)(NT * 64);

  f32x4 acc[2][2] = {};
  bf16x8 breg[4][2][2];                // static idx under full unroll (rule #20)
  const unsigned short* wlane = Wp + lane * 8;
  const int fb_n = ((bn0 + cn) >> 4);  // first n-tile of this wave

  auto stageA = [&](int buf, int tile) {   // 2 gload_lds / wave
    const int k0 = tile * BK;
#pragma unroll
    for (int j = 0; j < 2; ++j) {
      const int c = wid * 2 + j;                      // chunks 0..7 (8 rows)
      gload_lds16(A + (size_t)(bm0 + c * 8 + lr) * Kz + (k0 + scol),
                  &As[buf][c * 512]);
    }
  };

  auto loadB = [&](int slot, int tile) {   // 4 coalesced 16B-lane loads / wave
#pragma unroll
    for (int ni = 0; ni < 2; ++ni)
#pragma unroll
      for (int ks = 0; ks < 2; ++ks) {
        const size_t frag = (size_t)(fb_n + ni) * KT + tile * 2 + ks;
        breg[slot][ni][ks] =
            *reinterpret_cast<const bf16x8*>(wlane + frag * 512);
      }
  };

  auto compute = [&](int buf, int slot) {
    const int swz = (l15 & 7) << 3;   // same involution as scol
#pragma unroll
    for (int ks = 0; ks < 2; ++ks) {
      const int kidx = (ks * 32 + l4 * 8) ^ swz;
      bf16x8 a[2];
#pragma unroll
      for (int mi = 0; mi < 2; ++mi)
        a[mi] = *reinterpret_cast<const bf16x8*>(
            &As[buf][(rm + mi * 16 + l15) * 64 + kidx]);
#pragma unroll
      for (int mi = 0; mi < 2; ++mi)
#pragma unroll
        for (int ni = 0; ni < 2; ++ni)
          acc[mi][ni] = __builtin_amdgcn_mfma_f32_16x16x32_bf16(
              a[mi], breg[slot][ni][ks], acc[mi][ni], 0, 0, 0);
    }
  };

  // Prologue: tiles 0..2 issued as [A(p) 2ops, B(p) 4ops] -> 18 outstanding.
#pragma unroll
  for (int p = 0; p < 3; ++p) { stageA(p, p); loadB(p, p); }
#pragma unroll
  for (int t = 0; t < NT; ++t) {
    if (t + 3 < NT) { stageA((t + 3) % NA, t + 3); loadB((t + 3) & 3, t + 3); }
    const int rem = NT - 1 - t;   // tiles still in flight after this wait
    if (rem >= 3)      asm volatile("s_waitcnt vmcnt(18)" ::: "memory");
    else if (rem == 2) asm volatile("s_waitcnt vmcnt(12)" ::: "memory");
    else if (rem == 1) asm volatile("s_waitcnt vmcnt(6)" ::: "memory");
    else               asm volatile("s_waitcnt vmcnt(0)" ::: "memory");
    asm volatile("s_waitcnt lgkmcnt(0)" ::: "memory");  // my prior ds_reads
    __builtin_amdgcn_s_barrier();
    // stageA(t+3) overwrote As slot (t-2)%5, consumed 2 barriers ago: safe.
    compute(t % NA, t & 3);
  }

  if (EPI == 0) {
#pragma unroll
    for (int mi = 0; mi < 2; ++mi)
#pragma unroll
      for (int ni = 0; ni < 2; ++ni) {
        const int col = bn0 + cn + ni * 16 + l15;
        const float bcol = bias[col];
#pragma unroll
        for (int i = 0; i < 4; ++i) {
          const int row = bm0 + rm + mi * 16 + l4 * 4 + i;
          ((unsigned short*)outp)[(size_t)row * 2048 + col] =
              f2bf(acc[mi][ni][i] + bcol);
        }
      }
  } else {
    // Fused x32 broadcast: C tile (f32,+bias) -> LDS stride 68 -> 32x streams.
    asm volatile("s_waitcnt lgkmcnt(0)" ::: "memory");
    __builtin_amdgcn_s_barrier();          // all waves done reading As
    float* Cs = (float*)As;                // 17.4 KB of 40 KB
#pragma unroll
    for (int mi = 0; mi < 2; ++mi)
#pragma unroll
      for (int ni = 0; ni < 2; ++ni) {
        const int col = cn + ni * 16 + l15;
        const float bcol = bias[bn0 + col];
#pragma unroll
        for (int i = 0; i < 4; ++i)
          Cs[(rm + mi * 16 + l4 * 4 + i) * 68 + col] = acc[mi][ni][i] + bcol;
      }
    asm volatile("s_waitcnt lgkmcnt(0)" ::: "memory");
    __builtin_amdgcn_s_barrier();
    float* outf = (float*)outp;
    const int c4 = (lane & 15) * 4;
    const int psub = lane >> 4;
#pragma unroll
    for (int it = 0; it < 16; ++it) {
      const int rl = wid * 16 + it;
      const f32x4 v = *reinterpret_cast<const f32x4*>(&Cs[rl * 68 + c4]);
      float* ob = outf + ((size_t)(bm0 + rl) * 32 + psub) * 2048 + bn0 + c4;
#pragma unroll
      for (int pb = 0; pb < 8; ++pb)
        __builtin_nontemporal_store(
            v, reinterpret_cast<f32x4*>(ob + (size_t)pb * 4 * 2048));
    }
  }
}

extern "C" void kernel_launch(void* const* d_in, const int* in_sizes, int n_in,
                              void* d_out, int out_size, void* d_ws, size_t ws_size,
                              hipStream_t stream) {
  const float* image = (const float*)d_in[0];
  const float* Wm   = (const float*)d_in[1];
  const float* bm   = (const float*)d_in[2];
  // d_in[3] prefix_queries: dead (softmax over singleton axis)
  const float* Win  = (const float*)d_in[4];
  const float* bin  = (const float*)d_in[5];
  const float* Wo1  = (const float*)d_in[6];
  const float* bo1  = (const float*)d_in[7];
  const float* Wo2  = (const float*)d_in[8];
  const float* bo2  = (const float*)d_in[9];
  float* out = (float*)d_out;

  const float* Wv = Win + (size_t)2 * 2048 * 2048;
  const float* bv = bin + 2 * 2048;

  unsigned short* wsb = (unsigned short*)d_ws;
  unsigned short* Xb   = wsb;                  // 1M bf16 elems
  unsigned short* Wmb  = wsb + (1u << 20);     // 2M (packed)
  unsigned short* Wvb  = wsb + (3u << 20);     // 4M (packed)
  unsigned short* W1b  = wsb + (7u << 20);     // 4M (packed)
  unsigned short* W2b  = wsb + (11u << 20);    // 4M (packed)
  unsigned short* act0 = wsb + (15u << 20);    // 2M
  unsigned short* act1 = wsb + (17u << 20);    // 2M
  unsigned short* act2 = wsb + (19u << 20);    // 2M

  cvt_xw<<<1024, 256, 0, stream>>>(image, Wm, Xb, Wmb);

  gemm_bt<16, 0, true><<<GEMM_BLOCKS + PACK_BLOCKS, 256, 0, stream>>>(
      Xb, Wmb, bm, act0, Wv, Wvb, 524288);
  gemm_bt<32, 0, true><<<GEMM_BLOCKS + PACK_BLOCKS, 256, 0, stream>>>(
      act0, Wvb, bv, act1, Wo1, W1b, 524288);
  gemm_bt<32, 0, true><<<GEMM_BLOCKS + PACK_BLOCKS, 256, 0, stream>>>(
      act1, W1b, bo1, act2, Wo2, W2b, 524288);
  gemm_bt<32, 1, false><<<GEMM_BLOCKS, 256, 0, stream>>>(
      act2, W2b, bo2, out, nullptr, nullptr, 0);
  (void)n_in; (void)in_sizes; (void)out_size; (void)ws_size;
}

// Round 21
// 132.313 us; speedup vs baseline: 1.1405x; 1.1405x over previous
//
#include <hip/hip_runtime.h>

// CrossAttentionAdapter: softmax over a SINGLETON axis => attn == 1 =>
// out[b,p,:] = (((x@Wm^T+bm)@Wv^T+bv)@Wo_mha^T+bo_mha)@Wo^T+bo, independent of p.
// FINAL (= r18, measured best 132.4 us): cvt_xw | G1(+pack Wv) | G2(+pack Wo1)
// | G3(+pack Wo2) | G4 + fused x32 broadcast (268 MB).
// GEMM: 64x64 tile, 4 waves; A via 5-deep LDS ring (global_load_lds, XOR-
// swizzled source col, rule #21); B via packed-fragment depth-4 REGISTER ring
// (r15: halves LDS-port traffic — the binding resource); counted vmcnt
// 18/12/6/0 (never 0 in steady loop); ONE s_barrier/tile; 3 blocks/CU.
// Falsified alternatives: megakernel/grid.sync (r4: XCD coherence), B-reg from
// row-major W (r7: 16x L2 inflation), 1-tile cover (r10 cliff), BK=32 (r13),
// zero-LDS both-operand reg streaming (r17: 2x L2 traffic), concurrent pack
// blocks (r20: dispatch/XCD-map perturbation).

#define BM 64
#define BN 64
#define BK 64
#define NA 5

typedef __attribute__((ext_vector_type(8))) __bf16 bf16x8;
typedef __attribute__((ext_vector_type(8))) unsigned short u16x8;
typedef __attribute__((ext_vector_type(4))) float f32x4;

__device__ __forceinline__ unsigned short f2bf(float f) {
  unsigned int u = __float_as_uint(f);
  u += 0x7FFFu + ((u >> 16) & 1u);   // RNE
  return (unsigned short)(u >> 16);
}

__device__ __forceinline__ u16x8 cvt8(float4 v0, float4 v1) {
  u16x8 o;
  o[0] = f2bf(v0.x); o[1] = f2bf(v0.y); o[2] = f2bf(v0.z); o[3] = f2bf(v0.w);
  o[4] = f2bf(v1.x); o[5] = f2bf(v1.y); o[6] = f2bf(v1.z); o[7] = f2bf(v1.w);
  return o;
}

// Pack one 8-elem unit of row-major W[N][K] (f32) into MFMA-fragment order:
// frag = (n>>4)*(K/32) + (k>>5); lane = ((k>>3)&3)*16 + (n&15); 16B per lane.
template <int KLOG2>
__device__ __forceinline__ void pack_w8(const float* __restrict__ src,
                                        unsigned short* __restrict__ dst,
                                        size_t u) {
  const size_t n = u >> (KLOG2 - 3);
  const size_t ko = u & (((size_t)1 << (KLOG2 - 3)) - 1);   // k/8
  const float4 v0 = reinterpret_cast<const float4*>(src)[u * 2];
  const float4 v1 = reinterpret_cast<const float4*>(src)[u * 2 + 1];
  const size_t frag = (n >> 4) * ((size_t)1 << (KLOG2 - 5)) + (ko >> 2);
  const size_t lane = ((ko & 3) << 4) + (n & 15);
  reinterpret_cast<u16x8*>(dst)[frag * 64 + lane] = cvt8(v0, v1);
}

// X (1024x1024) -> bf16 row-major; Wm (2048x1024) -> packed fragments.
__global__ __launch_bounds__(256) void cvt_xw(const float* __restrict__ x,
                                              const float* __restrict__ wm,
                                              unsigned short* __restrict__ xb,
                                              unsigned short* __restrict__ wmb) {
  size_t u = (size_t)blockIdx.x * 256 + threadIdx.x;   // 262144 threads
  for (; u < 393216; u += 262144) {
    if (u < 131072) {
      const float4 v0 = reinterpret_cast<const float4*>(x)[u * 2];
      const float4 v1 = reinterpret_cast<const float4*>(x)[u * 2 + 1];
      reinterpret_cast<u16x8*>(xb)[u] = cvt8(v0, v1);
    } else {
      pack_w8<10>(wm, wmb, u - 131072);
    }
  }
}

__device__ __forceinline__ void gload_lds16(const void* g, void* l) {
  __builtin_amdgcn_global_load_lds(
      (const __attribute__((address_space(1))) void*)g,
      (__attribute__((address_space(3))) void*)l, 16, 0, 0);
}

// C = A (MxK bf16 row-major) * W^T + bias; Wp = packed fragments; K = NT*64.
// A: 5-deep LDS ring (swizzled source col, rule #21). B: 4-slot VGPR ring,
// statically indexed (full unroll). 6 vmem ops/tile (2 gload_lds + 4 b128);
// counted waits: steady vmcnt(18) (3 tiles in flight), tails 12/6/0.
// EPI=0: bf16 store. EPI=1: fused x32 broadcast via LDS re-stage.
// CVT: pack NEXT GEMM's W (f32 -> packed bf16 fragments) as a tail.
template <int NT, int EPI, bool CVT>
__global__ __launch_bounds__(256, 3) void gemm_bt(
    const unsigned short* __restrict__ A, const unsigned short* __restrict__ Wp,
    const float* __restrict__ bias, void* __restrict__ outp,
    const float* __restrict__ cvt_src, unsigned short* __restrict__ cvt_dst,
    int cvt_nu) {
  __shared__ __attribute__((aligned(16))) unsigned short As[NA][BM * BK];
  const int tid = threadIdx.x;
  const int lane = tid & 63;
  const int wid = tid >> 6;          // 4 waves, 2x2
  const int rm = (wid >> 1) * 32;    // wave row group
  const int cn = (wid & 1) * 32;     // wave col group
  const int bid = blockIdx.x;
  // XCD = bid&7 owns 4 N-tiles (256-col W panel, L2-resident over 16 M-blocks)
  const int bn0 = ((bid & 7) * 4 + (bid >> 7)) * BN;
  const int bm0 = ((bid >> 3) & 15) * BM;
  const int l15 = lane & 15;
  const int l4 = lane >> 4;
  const int lr = lane >> 3;
  const int lc = lane & 7;
  const int scol = ((lc ^ lr) << 3);   // pre-swizzled A source col (rule #21)
  const int KT = NT * 2;               // k-fragments per n-tile row
  const size_t Kz = (size_t)(NT * 64);

  f32x4 acc[2][2] = {};
  bf16x8 breg[4][2][2];                // static idx under full unroll (rule #20)
  const unsigned short* wlane = Wp + lane * 8;
  const int fb_n = ((bn0 + cn) >> 4);  // first n-tile of this wave

  auto stageA = [&](int buf, int tile) {   // 2 gload_lds / wave
    const int k0 = tile * BK;
#pragma unroll
    for (int j = 0; j < 2; ++j) {
      const int c = wid * 2 + j;                      // chunks 0..7 (8 rows)
      gload_lds16(A + (size_t)(bm0 + c * 8 + lr) * Kz + (k0 + scol),
                  &As[buf][c * 512]);
    }
  };

  auto loadB = [&](int slot, int tile) {   // 4 coalesced 16B-lane loads / wave
#pragma unroll
    for (int ni = 0; ni < 2; ++ni)
#pragma unroll
      for (int ks = 0; ks < 2; ++ks) {
        const size_t frag = (size_t)(fb_n + ni) * KT + tile * 2 + ks;
        breg[slot][ni][ks] =
            *reinterpret_cast<const bf16x8*>(wlane + frag * 512);
      }
  };

  auto compute = [&](int buf, int slot) {
    const int swz = (l15 & 7) << 3;   // same involution as scol
#pragma unroll
    for (int ks = 0; ks < 2; ++ks) {
      const int kidx = (ks * 32 + l4 * 8) ^ swz;
      bf16x8 a[2];
#pragma unroll
      for (int mi = 0; mi < 2; ++mi)
        a[mi] = *reinterpret_cast<const bf16x8*>(
            &As[buf][(rm + mi * 16 + l15) * 64 + kidx]);
#pragma unroll
      for (int mi = 0; mi < 2; ++mi)
#pragma unroll
        for (int ni = 0; ni < 2; ++ni)
          acc[mi][ni] = __builtin_amdgcn_mfma_f32_16x16x32_bf16(
              a[mi], breg[slot][ni][ks], acc[mi][ni], 0, 0, 0);
    }
  };

  // Prologue: tiles 0..2 issued as [A(p) 2ops, B(p) 4ops] -> 18 outstanding.
#pragma unroll
  for (int p = 0; p < 3; ++p) { stageA(p, p); loadB(p, p); }
#pragma unroll
  for (int t = 0; t < NT; ++t) {
    if (t + 3 < NT) { stageA((t + 3) % NA, t + 3); loadB((t + 3) & 3, t + 3); }
    const int rem = NT - 1 - t;   // tiles still in flight after this wait
    if (rem >= 3)      asm volatile("s_waitcnt vmcnt(18)" ::: "memory");
    else if (rem == 2) asm volatile("s_waitcnt vmcnt(12)" ::: "memory");
    else if (rem == 1) asm volatile("s_waitcnt vmcnt(6)" ::: "memory");
    else               asm volatile("s_waitcnt vmcnt(0)" ::: "memory");
    asm volatile("s_waitcnt lgkmcnt(0)" ::: "memory");  // my prior ds_reads
    __builtin_amdgcn_s_barrier();
    // stageA(t+3) overwrote As slot (t-2)%5, consumed 2 barriers ago: safe.
    compute(t % NA, t & 3);
  }

  if (EPI == 0) {
#pragma unroll
    for (int mi = 0; mi < 2; ++mi)
#pragma unroll
      for (int ni = 0; ni < 2; ++ni) {
        const int col = bn0 + cn + ni * 16 + l15;
        const float bcol = bias[col];
#pragma unroll
        for (int i = 0; i < 4; ++i) {
          const int row = bm0 + rm + mi * 16 + l4 * 4 + i;
          ((unsigned short*)outp)[(size_t)row * 2048 + col] =
              f2bf(acc[mi][ni][i] + bcol);
        }
      }
  } else {
    // Fused x32 broadcast: C tile (f32,+bias) -> LDS stride 68 -> 32x streams.
    asm volatile("s_waitcnt lgkmcnt(0)" ::: "memory");
    __builtin_amdgcn_s_barrier();          // all waves done reading As
    float* Cs = (float*)As;                // 17.4 KB of 40 KB
#pragma unroll
    for (int mi = 0; mi < 2; ++mi)
#pragma unroll
      for (int ni = 0; ni < 2; ++ni) {
        const int col = cn + ni * 16 + l15;
        const float bcol = bias[bn0 + col];
#pragma unroll
        for (int i = 0; i < 4; ++i)
          Cs[(rm + mi * 16 + l4 * 4 + i) * 68 + col] = acc[mi][ni][i] + bcol;
      }
    asm volatile("s_waitcnt lgkmcnt(0)" ::: "memory");
    __builtin_amdgcn_s_barrier();
    float* outf = (float*)outp;
    const int c4 = (lane & 15) * 4;
    const int psub = lane >> 4;
#pragma unroll
    for (int it = 0; it < 16; ++it) {
      const int rl = wid * 16 + it;
      const f32x4 v = *reinterpret_cast<const f32x4*>(&Cs[rl * 68 + c4]);
      float* ob = outf + ((size_t)(bm0 + rl) * 32 + psub) * 2048 + bn0 + c4;
#pragma unroll
      for (int pb = 0; pb < 8; ++pb)
        __builtin_nontemporal_store(
            v, reinterpret_cast<f32x4*>(ob + (size_t)pb * 4 * 2048));
    }
  }

  if (CVT) {   // pack next GEMM's W (K=2048); kernel boundary publishes it
    size_t u = (size_t)bid * 256 + tid;
    for (; u < (size_t)cvt_nu; u += 131072) pack_w8<11>(cvt_src, cvt_dst, u);
  }
}

extern "C" void kernel_launch(void* const* d_in, const int* in_sizes, int n_in,
                              void* d_out, int out_size, void* d_ws, size_t ws_size,
                              hipStream_t stream) {
  const float* image = (const float*)d_in[0];
  const float* Wm   = (const float*)d_in[1];
  const float* bm   = (const float*)d_in[2];
  // d_in[3] prefix_queries: dead (softmax over singleton axis)
  const float* Win  = (const float*)d_in[4];
  const float* bin  = (const float*)d_in[5];
  const float* Wo1  = (const float*)d_in[6];
  const float* bo1  = (const float*)d_in[7];
  const float* Wo2  = (const float*)d_in[8];
  const float* bo2  = (const float*)d_in[9];
  float* out = (float*)d_out;

  const float* Wv = Win + (size_t)2 * 2048 * 2048;
  const float* bv = bin + 2 * 2048;

  unsigned short* wsb = (unsigned short*)d_ws;
  unsigned short* Xb   = wsb;                  // 1M bf16 elems
  unsigned short* Wmb  = wsb + (1u << 20);     // 2M (packed)
  unsigned short* Wvb  = wsb + (3u << 20);     // 4M (packed)
  unsigned short* W1b  = wsb + (7u << 20);     // 4M (packed)
  unsigned short* W2b  = wsb + (11u << 20);    // 4M (packed)
  unsigned short* act0 = wsb + (15u << 20);    // 2M
  unsigned short* act1 = wsb + (17u << 20);    // 2M
  unsigned short* act2 = wsb + (19u << 20);    // 2M

  cvt_xw<<<1024, 256, 0, stream>>>(image, Wm, Xb, Wmb);

  gemm_bt<16, 0, true><<<512, 256, 0, stream>>>(Xb, Wmb, bm, act0,
                                                Wv, Wvb, 524288);
  gemm_bt<32, 0, true><<<512, 256, 0, stream>>>(act0, Wvb, bv, act1,
                                                Wo1, W1b, 524288);
  gemm_bt<32, 0, true><<<512, 256, 0, stream>>>(act1, W1b, bo1, act2,
                                                Wo2, W2b, 524288);
  gemm_bt<32, 1, false><<<512, 256, 0, stream>>>(act2, W2b, bo2, out,
                                                 nullptr, nullptr, 0);
  (void)n_in; (void)in_sizes; (void)out_size; (void)ws_size;
}